// Round 5
// baseline (520.660 us; speedup 1.0000x reference)
//
#include <hip/hip_runtime.h>

#define BB 4
#define CC 1024
#define TT 1024
#define HH 16
#define DD 64

typedef __bf16 v8bf __attribute__((ext_vector_type(8)));
typedef __bf16 v4bf __attribute__((ext_vector_type(4)));
typedef float  v4f  __attribute__((ext_vector_type(4)));

// async global->LDS, 16B per lane; LDS dest = wave-uniform base + lane*16
__device__ __forceinline__ void gl_lds16(const __bf16* g, __bf16* l) {
  __builtin_amdgcn_global_load_lds(
      (const __attribute__((address_space(1))) void*)g,
      (__attribute__((address_space(3))) void*)l, 16, 0, 0);
}

// ---- prep_all: mask expand (blk 0) + weight casts (1..2048) + x transpose --
__global__ __launch_bounds__(256) void prep_all(
    const void* mraw, float* __restrict__ maskf,
    const float* __restrict__ w_kvq, const float* __restrict__ w_out,
    __bf16* __restrict__ wkb, __bf16* __restrict__ wob,
    const float* __restrict__ x, __bf16* __restrict__ xT)
{
  const int blk = blockIdx.x;
  const int tid = threadIdx.x;
  if (blk == 0) {
    __shared__ int flagA, flagB;
    if (tid == 0) { flagA = 0; flagB = 0; }
    __syncthreads();
    const unsigned char* mb = (const unsigned char*)mraw;
    const int n = BB * TT;
    int a = 0, bfl = 0;
    for (int i = tid; i < n; i += 256) {
      if (mb[i]) { if ((i & 3) == 0) a = 1; else bfl = 1; }
    }
    if (a)   atomicOr(&flagA, 1);
    if (bfl) atomicOr(&flagB, 1);
    __syncthreads();
    int layout;                         // 0=int32, 1=float32, 2=uint8
    if (flagA && !flagB)      layout = 0;
    else if (!flagA && flagB) layout = 1;
    else                      layout = 2;
    for (int i = tid; i < n; i += 256) {
      float m;
      if (layout == 0)      m = (((const int*)mraw)[i]   != 0)   ? 1.f : 0.f;
      else if (layout == 1) m = (((const float*)mraw)[i] != 0.f) ? 1.f : 0.f;
      else                  m = (mb[i] != 0)                     ? 1.f : 0.f;
      maskf[i] = m;
    }
    return;
  }
  if (blk <= 2048) {                    // weight casts
    long i = ((long)blk - 1) * 2048 + tid * 8;
    const float* src;
    __bf16* dst;
    if (i < (long)3 * CC * CC) { src = w_kvq + i; dst = wkb + i; }
    else { long j = i - (long)3 * CC * CC; src = w_out + j; dst = wob + j; }
    float4 f0 = *(const float4*)src;
    float4 f1 = *(const float4*)(src + 4);
    v8bf o;
    o[0] = (__bf16)f0.x; o[1] = (__bf16)f0.y; o[2] = (__bf16)f0.z; o[3] = (__bf16)f0.w;
    o[4] = (__bf16)f1.x; o[5] = (__bf16)f1.y; o[6] = (__bf16)f1.z; o[7] = (__bf16)f1.w;
    *(v8bf*)dst = o;
    return;
  }
  // transpose_x: x [b][c][t] fp32 -> xT [b][t][c] bf16
  const int tb = blk - 2049;            // 0..1023
  const int b = tb >> 8;
  const int t0 = (tb & 15) * 64, c0 = ((tb >> 4) & 15) * 64;
  __shared__ __bf16 T[64][72];
  {
    int row = tid >> 2, coff = (tid & 3) * 16;
    const float* src = x + ((long)b * CC + c0 + row) * TT + t0 + coff;
#pragma unroll
    for (int s = 0; s < 4; s++) {
      float4 f = *(const float4*)(src + s * 4);
      T[row][coff + s * 4 + 0] = (__bf16)f.x;
      T[row][coff + s * 4 + 1] = (__bf16)f.y;
      T[row][coff + s * 4 + 2] = (__bf16)f.z;
      T[row][coff + s * 4 + 3] = (__bf16)f.w;
    }
  }
  __syncthreads();
  {
    int trow = tid >> 2, ccoff = (tid & 3) * 16;
    __bf16 vals[16];
#pragma unroll
    for (int i = 0; i < 16; i++) vals[i] = T[ccoff + i][trow];
    __bf16* dst = xT + ((long)b * TT + t0 + trow) * CC + c0 + ccoff;
    *(v8bf*)dst       = *(v8bf*)&vals[0];
    *(v8bf*)(dst + 8) = *(v8bf*)&vals[8];
  }
}

// ------- MFMA GEMM: C[m][n] = sum_k A[m][k]*BT[n][k], K=1024, BK=64 --------
// MODE 0 (kvq): k/q thirds -> kqT[t][2C] (LDS-transposed), v third -> vbuf[c][t]
// MODE 1 (out): fp32 out = acc + S (nontemporal)
template <int MODE>
__global__ __launch_bounds__(256) void gemm_bt(
    const __bf16* __restrict__ A, const __bf16* __restrict__ BTfull,
    const float* __restrict__ Sfull, float* __restrict__ Ofull,
    __bf16* __restrict__ kqT, __bf16* __restrict__ vbuf,
    long strideBT)
{
  const int bz = blockIdx.z;
  const __bf16* BT = BTfull + (long)bz * strideBT;
  const int m0 = blockIdx.y * 128, n0 = blockIdx.x * 128;
  __shared__ __align__(16) char smem[(MODE == 0) ? 34816 : 32768];
  __bf16 (*As)[128][32] = (__bf16(*)[128][32])smem;             // 2 x 8 KB
  __bf16 (*Bs)[128][32] = (__bf16(*)[128][32])(smem + 16384);   // 2 x 8 KB
  const int tid = threadIdx.x;
  const int lane = tid & 63, wave = tid >> 6;
  const int wm = wave >> 1, wn = wave & 1;
  const int ln = lane & 15, q = lane >> 4;

  v4f acc[4][4];
#pragma unroll
  for (int i = 0; i < 4; i++)
#pragma unroll
    for (int j = 0; j < 4; j++) acc[i][j] = (v4f)(0.f);

  const int lr = lane >> 2;          // row within 16-row chunk
  const int lc = (lane & 3) * 8;     // col element within 32
  for (int k0 = 0; k0 < CC; k0 += 64) {
#pragma unroll
    for (int s = 0; s < 2; s++) {
      int row = wave * 32 + s * 16;
#pragma unroll
      for (int kd = 0; kd < 2; kd++) {
        gl_lds16(A  + (long)(m0 + row + lr) * CC + k0 + kd * 32 + lc, &As[kd][row][0]);
        gl_lds16(BT + (long)(n0 + row + lr) * CC + k0 + kd * 32 + lc, &Bs[kd][row][0]);
      }
    }
    __syncthreads();
    v8bf af[4][2], bf[4][2];
#pragma unroll
    for (int mi = 0; mi < 4; mi++)
#pragma unroll
      for (int kd = 0; kd < 2; kd++)
        af[mi][kd] = *(v8bf*)&As[kd][wm * 64 + mi * 16 + ln][q * 8];
#pragma unroll
    for (int ni = 0; ni < 4; ni++)
#pragma unroll
      for (int kd = 0; kd < 2; kd++)
        bf[ni][kd] = *(v8bf*)&Bs[kd][wn * 64 + ni * 16 + ln][q * 8];
#pragma unroll
    for (int mi = 0; mi < 4; mi++)
#pragma unroll
      for (int ni = 0; ni < 4; ni++) {
        acc[mi][ni] = __builtin_amdgcn_mfma_f32_16x16x32_bf16(af[mi][0], bf[ni][0], acc[mi][ni], 0, 0, 0);
        acc[mi][ni] = __builtin_amdgcn_mfma_f32_16x16x32_bf16(af[mi][1], bf[ni][1], acc[mi][ni], 0, 0, 0);
      }
    __syncthreads();
  }

  if (MODE == 1) {
#pragma unroll
    for (int mi = 0; mi < 4; mi++)
#pragma unroll
      for (int ni = 0; ni < 4; ni++)
#pragma unroll
        for (int r = 0; r < 4; r++) {
          long off = (long)bz * CC * TT + (long)(m0 + wm * 64 + mi * 16 + q * 4 + r) * TT
                   + n0 + wn * 64 + ni * 16 + ln;
          __builtin_nontemporal_store(acc[mi][ni][r] + Sfull[off], &Ofull[off]);
        }
  } else {
    const int third = m0 >> 10;                      // 0=k, 1=v, 2=q
    if (third == 1) {
      const int mb = m0 - 1024;
#pragma unroll
      for (int mi = 0; mi < 4; mi++)
#pragma unroll
        for (int ni = 0; ni < 4; ni++)
#pragma unroll
          for (int r = 0; r < 4; r++)
            vbuf[((long)bz * CC + mb + wm * 64 + mi * 16 + q * 4 + r) * TT
                 + n0 + wn * 64 + ni * 16 + ln] = (__bf16)acc[mi][ni][r];
    } else {
      __bf16 (*Tl)[136] = (__bf16(*)[136])smem;      // 128x136 bf16 = 34 KB
#pragma unroll
      for (int mi = 0; mi < 4; mi++)
#pragma unroll
        for (int ni = 0; ni < 4; ni++) {
          v4bf pb;
#pragma unroll
          for (int r = 0; r < 4; r++) pb[r] = (__bf16)acc[mi][ni][r];
          *(v4bf*)&Tl[wn * 64 + ni * 16 + ln][wm * 64 + mi * 16 + q * 4] = pb;
        }
      __syncthreads();
      const int dstbase = (third == 0) ? 0 : CC;
      const int mcol = (third == 0) ? m0 : (m0 - 2048);
      int t = tid >> 1, c0 = (tid & 1) * 64;
      __bf16* drow = kqT + ((long)bz * TT + n0 + t) * (2 * CC) + dstbase + mcol + c0;
#pragma unroll
      for (int s = 0; s < 8; s++)
        *(v8bf*)(drow + s * 8) = *(v8bf*)&Tl[t][c0 + s * 8];
    }
  }
}

// ---- attn_fused: per-wave 16 query cols; phase1 online (M,S); phase2 ------
// recompute logits (bit-identical), att <- p (nontemporal), o^T += p^T v^T.
__global__ __launch_bounds__(256) void attn_fused(
    const __bf16* __restrict__ kqT, const __bf16* __restrict__ vbuf,
    const float* __restrict__ maskf, float* __restrict__ att,
    __bf16* __restrict__ oT)
{
  const int z = blockIdx.y, h = z >> 2, b = z & 3;
  const int j0 = blockIdx.x * 64;
  const int tid = threadIdx.x;
  const int lane = tid & 63, wave = tid >> 6;
  const int ln = lane & 15, q = lane >> 4;
  __shared__ float km[1024];                           // key/query mask (same array)
  __shared__ __bf16 PtAll[4][16][72];                  // per-wave p-tile [j][i]

  const __bf16* kbase = kqT + (long)b * TT * (2 * CC);
  const __bf16* vbase = vbuf + ((long)b * CC + h * DD) * TT;
  const int jw = j0 + wave * 16;                       // wave's 16 query cols

  *(float4*)&km[tid * 4] = *(const float4*)(maskf + b * TT + tid * 4);
  __syncthreads();

  // q fragment for this wave's j-range (read once)
  v8bf bq[2];
#pragma unroll
  for (int kd = 0; kd < 2; kd++)
    bq[kd] = *(const v8bf*)(kbase + (long)(jw + ln) * (2 * CC) + CC + h * DD + kd * 32 + q * 8);

  // ---------------- phase 1: online (M,S) over all 1024 keys ---------------
  float rm = -3.4e38f, rs = 0.f;
  for (int it = 0; it < 16; it++) {
    const int ibase = it * 64;
    float lv[16];
    float cm = -3.4e38f;
#pragma unroll
    for (int mi = 0; mi < 4; mi++) {
      const __bf16* arow = kbase + (long)(ibase + mi * 16 + ln) * (2 * CC) + h * DD;
      v8bf ak0 = *(const v8bf*)(arow + q * 8);
      v8bf ak1 = *(const v8bf*)(arow + 32 + q * 8);
      v4f l4 = (v4f)(0.f);
      l4 = __builtin_amdgcn_mfma_f32_16x16x32_bf16(ak0, bq[0], l4, 0, 0, 0);
      l4 = __builtin_amdgcn_mfma_f32_16x16x32_bf16(ak1, bq[1], l4, 0, 0, 0);
#pragma unroll
      for (int r = 0; r < 4; r++) {
        int i = ibase + mi * 16 + q * 4 + r;
        float l = (km[i] != 0.f) ? -1e30f : l4[r] * 0.125f;
        lv[mi * 4 + r] = l;
        cm = fmaxf(cm, l);
      }
    }
    float nm = fmaxf(rm, cm);
    float s = 0.f;
#pragma unroll
    for (int i = 0; i < 16; i++) s += __expf(lv[i] - nm);
    rs = rs * __expf(rm - nm) + s;
    rm = nm;
  }
  // reduce across row-quads (q-splits of i)
#pragma unroll
  for (int off = 16; off <= 32; off <<= 1) {
    float om = __shfl_xor(rm, off, 64);
    float os = __shfl_xor(rs, off, 64);
    float M = fmaxf(rm, om);
    rs = rs * __expf(rm - M) + os * __expf(om - M);
    rm = M;
  }
  const float qz = (km[jw + ln] != 0.f) ? 0.f : 1.f;   // post-softmax query mask
  const float Mf = rm, iS = qz / rs;

  // ------- phase 2: recompute logits, att <- p, o^T accumulation -----------
  v4f acc[4];
#pragma unroll
  for (int di = 0; di < 4; di++) acc[di] = (v4f)(0.f);
  __bf16 (*Pt)[72] = PtAll[wave];

  for (int it = 0; it < 16; it++) {
    const int ibase = it * 64;
#pragma unroll
    for (int mi = 0; mi < 4; mi++) {
      const __bf16* arow = kbase + (long)(ibase + mi * 16 + ln) * (2 * CC) + h * DD;
      v8bf ak0 = *(const v8bf*)(arow + q * 8);
      v8bf ak1 = *(const v8bf*)(arow + 32 + q * 8);
      v4f l4 = (v4f)(0.f);
      l4 = __builtin_amdgcn_mfma_f32_16x16x32_bf16(ak0, bq[0], l4, 0, 0, 0);
      l4 = __builtin_amdgcn_mfma_f32_16x16x32_bf16(ak1, bq[1], l4, 0, 0, 0);
      v4bf pb;
#pragma unroll
      for (int r = 0; r < 4; r++) {
        int i = ibase + mi * 16 + q * 4 + r;
        float l = (km[i] != 0.f) ? -1e30f : l4[r] * 0.125f;
        float p = __expf(l - Mf) * iS;
        __builtin_nontemporal_store(p, att + ((long)z << 20) + (long)i * TT + jw + ln);
        pb[r] = (__bf16)p;
      }
      *(v4bf*)&Pt[ln][mi * 16 + q * 4] = pb;
    }
    // same-wave LDS RAW: compiler inserts lgkmcnt wait; no barrier needed
    v8bf ap[2];
#pragma unroll
    for (int kd = 0; kd < 2; kd++) ap[kd] = *(v8bf*)&Pt[ln][kd * 32 + q * 8];
#pragma unroll
    for (int di = 0; di < 4; di++) {
      v8bf bv0 = *(const v8bf*)(vbase + (long)(di * 16 + ln) * TT + ibase + q * 8);
      v8bf bv1 = *(const v8bf*)(vbase + (long)(di * 16 + ln) * TT + ibase + 32 + q * 8);
      acc[di] = __builtin_amdgcn_mfma_f32_16x16x32_bf16(ap[0], bv0, acc[di], 0, 0, 0);
      acc[di] = __builtin_amdgcn_mfma_f32_16x16x32_bf16(ap[1], bv1, acc[di], 0, 0, 0);
    }
  }

  // epilogue: lane (q,ln) holds o[j = jw+q*4+r][d = di*16+ln]
#pragma unroll
  for (int r = 0; r < 4; r++) {
    __bf16* drow = oT + ((long)b * TT + jw + q * 4 + r) * CC + h * DD;
#pragma unroll
    for (int di = 0; di < 4; di++)
      drow[di * 16 + ln] = (__bf16)acc[di][r];
  }
}

extern "C" void kernel_launch(void* const* d_in, const int* in_sizes, int n_in,
                              void* d_out, int out_size, void* d_ws, size_t ws_size,
                              hipStream_t stream) {
  const float* x     = (const float*)d_in[0];
  const void*  mask  = d_in[1];
  const float* w_kvq = (const float*)d_in[2];
  const float* w_out = (const float*)d_in[3];

  float* out = (float*)d_out;                     // [BB, CC, TT]
  float* att = out + (long)BB * CC * TT;          // [HH*BB, TT, TT]

  char* wsb = (char*)d_ws;
  float*   maskf = (float*)(wsb + 0);             // 16 KB
  __bf16*  wkb   = (__bf16*)(wsb + 16384);        // 6 MB
  __bf16*  wob   = (__bf16*)(wsb + 6307840);      // 2 MB
  __bf16*  xT    = (__bf16*)(wsb + 8404992);      // 8 MB  [b][t][c]
  __bf16*  kqT   = (__bf16*)(wsb + 16793600);     // 16 MB [b][t][2C] (k | q)
  __bf16*  vbuf  = (__bf16*)(wsb + 33570816);     // 8 MB  [b][c][t]
  __bf16*  oT    = (__bf16*)(wsb + 41959424);     // 8 MB  [b][t][c]

  // mask expand + weight casts + x transpose (one launch)
  prep_all<<<3073, 256, 0, stream>>>(mask, maskf, w_kvq, w_out, wkb, wob, x, xT);
  // kvq GEMM: k/q -> kqT (transposed epilogue), v -> vbuf
  gemm_bt<0><<<dim3(8, 24, BB), 256, 0, stream>>>(
      wkb, xT, nullptr, nullptr, kqT, vbuf, (long)CC * TT);
  // fused softmax-stats + att write + PV
  attn_fused<<<dim3(16, HH * BB), 256, 0, stream>>>(kqT, vbuf, maskf, att, oT);
  // out = x + w_out · o
  gemm_bt<1><<<dim3(8, 8, BB), 256, 0, stream>>>(
      wob, oT, x, out, nullptr, nullptr, (long)CC * TT);
}